// Round 8
// baseline (92.500 us; speedup 1.0000x reference)
//
#include <hip/hip_runtime.h>

// GeodesicConv via counting-sort by filter bin.
// R8: k_gemm = 2 points/thread + LDS-staged features.
//   - W ds_read (2xb128 per c) now feeds 16 FMAs (2 pts x 8 d) -> LDS W
//     traffic per FLOP halved vs R7.
//   - features staged once per block (coalesced), read w/ XOR swizzle
//     (c4 ^ (row&7)) -> 2-way-max bank alias (free), kills the 4x redundant
//     global feature gather of R7.
//   - two-flag ballot loop: pair may straddle a bin boundary; inactive point
//     contributes fmaf(0,w) == exact. c ascending => bit-identical to ref.

#define NBINS 40
#define NB_MAX 4
#define PTS_BLK 128
#define MAX_NBLK 128

__device__ __forceinline__ int bin_of(float2 rc) {
    const float TWO_PI_F = (float)(2.0 * 3.14159);
    int ri = (int)(rc.x * 5.0f);
    ri = min(max(ri, 0), 4);
    int oi = (int)((rc.y * 8.0f) / TWO_PI_F);
    oi = min(max(oi, 0), 7);
    return ri * 8 + oi;
}

__global__ __launch_bounds__(1024)
void k_hist(const float2* __restrict__ coords, int* __restrict__ hist,
            unsigned char* __restrict__ bins_u8, int npts) {
    __shared__ int h[NBINS];
    const int tid = threadIdx.x;
    if (tid < NBINS) h[tid] = 0;
    __syncthreads();
    const int p = blockIdx.x * 1024 + tid;
    if (p < npts) {
        const int b = bin_of(coords[p]);
        bins_u8[p] = (unsigned char)b;
        atomicAdd(&h[b], 1);
    }
    __syncthreads();
    if (tid < NBINS) hist[blockIdx.x * NBINS + tid] = h[tid];
}

__global__ __launch_bounds__(1024)
void k_scan(const int* __restrict__ hist, int* __restrict__ blkoff, int nblk) {
    __shared__ int lh[MAX_NBLK * NBINS];
    __shared__ int btot[NBINS];
    __shared__ int base[NBINS];
    const int tid  = threadIdx.x;
    const int wave = tid >> 6;
    const int lane = tid & 63;
    for (int i = tid; i < nblk * NBINS; i += 1024) lh[i] = hist[i];
    __syncthreads();
    for (int b = wave; b < NBINS; b += 16) {     // one wave per bin
        int v0 = lh[lane * NBINS + b];
        int v1 = lh[(64 + lane) * NBINS + b];
        #pragma unroll
        for (int off = 1; off < 64; off <<= 1) { int t = __shfl_up(v0, off); if (lane >= off) v0 += t; }
        const int tot0 = __shfl(v0, 63);
        #pragma unroll
        for (int off = 1; off < 64; off <<= 1) { int t = __shfl_up(v1, off); if (lane >= off) v1 += t; }
        const int total = __shfl(v1, 63) + tot0;
        int e0 = __shfl_up(v0, 1); if (lane == 0) e0 = 0;
        int e1 = __shfl_up(v1, 1); if (lane == 0) e1 = 0;
        e1 += tot0;
        lh[lane * NBINS + b] = e0;
        lh[(64 + lane) * NBINS + b] = e1;
        if (lane == 0) btot[b] = total;
    }
    __syncthreads();
    if (wave == 0) {
        int v = (lane < NBINS) ? btot[lane] : 0;
        #pragma unroll
        for (int off = 1; off < 64; off <<= 1) { int t = __shfl_up(v, off); if (lane >= off) v += t; }
        int e = __shfl_up(v, 1); if (lane == 0) e = 0;
        if (lane < NBINS) base[lane] = e;
    }
    __syncthreads();
    for (int i = tid; i < nblk * NBINS; i += 1024) {
        const int b = i - (i / NBINS) * NBINS;
        blkoff[i] = lh[i] + base[b];
    }
}

__global__ __launch_bounds__(1024)
void k_scatter(const unsigned char* __restrict__ bins_u8, const int* __restrict__ blkoff,
               int* __restrict__ sorted_pk, int npts) {
    __shared__ int off[NBINS];
    __shared__ int cnt[NBINS];
    const int tid = threadIdx.x;
    if (tid < NBINS) { off[tid] = blkoff[blockIdx.x * NBINS + tid]; cnt[tid] = 0; }
    __syncthreads();
    const int p = blockIdx.x * 1024 + tid;
    if (p < npts) {
        const int b = (int)bins_u8[p];
        const int r = atomicAdd(&cnt[b], 1);
        sorted_pk[off[b] + r] = p | (b << 20);
    }
}

// One bin-pass of the 2-point x 8-d micro-kernel. aA/aB mask inactive points
// (fmaf(0,w,acc) is exact). Feature reads swizzled: col' = c4 ^ (pp&7).
#define GEMM_PASS(W4BASE)                                                     \
    _Pragma("unroll")                                                         \
    for (int c4 = 0; c4 < 8; ++c4) {                                          \
        const int sw = c4 ^ swz;                                              \
        const float4 fA4 = Fl[pp * 8 + sw];                                   \
        const float4 fB4 = Fl[(pp + 64) * 8 + sw];                            \
        const float fA[4] = {aA ? fA4.x : 0.f, aA ? fA4.y : 0.f,              \
                             aA ? fA4.z : 0.f, aA ? fA4.w : 0.f};             \
        const float fB[4] = {aB ? fB4.x : 0.f, aB ? fB4.y : 0.f,              \
                             aB ? fB4.z : 0.f, aB ? fB4.w : 0.f};             \
        _Pragma("unroll")                                                     \
        for (int j = 0; j < 4; ++j) {                                         \
            const int c = c4 * 4 + j;                                         \
            const float4 w0 = (W4BASE)[c * 8 + q * 2 + 0];                    \
            const float4 w1 = (W4BASE)[c * 8 + q * 2 + 1];                    \
            acc[0]  = fmaf(fA[j], w0.x, acc[0]);                              \
            acc[1]  = fmaf(fA[j], w0.y, acc[1]);                              \
            acc[2]  = fmaf(fA[j], w0.z, acc[2]);                              \
            acc[3]  = fmaf(fA[j], w0.w, acc[3]);                              \
            acc[4]  = fmaf(fA[j], w1.x, acc[4]);                              \
            acc[5]  = fmaf(fA[j], w1.y, acc[5]);                              \
            acc[6]  = fmaf(fA[j], w1.z, acc[6]);                              \
            acc[7]  = fmaf(fA[j], w1.w, acc[7]);                              \
            acc[8]  = fmaf(fB[j], w0.x, acc[8]);                              \
            acc[9]  = fmaf(fB[j], w0.y, acc[9]);                              \
            acc[10] = fmaf(fB[j], w0.z, acc[10]);                             \
            acc[11] = fmaf(fB[j], w0.w, acc[11]);                             \
            acc[12] = fmaf(fB[j], w1.x, acc[12]);                             \
            acc[13] = fmaf(fB[j], w1.y, acc[13]);                             \
            acc[14] = fmaf(fB[j], w1.z, acc[14]);                             \
            acc[15] = fmaf(fB[j], w1.w, acc[15]);                             \
        }                                                                     \
    }

__global__ __launch_bounds__(256, 4)
void k_gemm(const float* __restrict__ feat, const float* __restrict__ filt,
            const float* __restrict__ bias, const int* __restrict__ sorted_pk,
            float* __restrict__ out) {
    __shared__ float4 Wl[NB_MAX * 256];   // 16 KB  (<=4 bins of W)
    __shared__ float4 Fl[PTS_BLK * 8];    // 16 KB  features [row][c4^swz]
    __shared__ int    Pidx[PTS_BLK];
    __shared__ int    Pbin[PTS_BLK];

    const int tid     = threadIdx.x;
    const int blkbase = blockIdx.x * PTS_BLK;

    if (tid < PTS_BLK) {
        const int pk = sorted_pk[blkbase + tid];
        Pidx[tid] = pk & 0xFFFFF;
        Pbin[tid] = pk >> 20;
    }
    __syncthreads();

    const int b0 = Pbin[0];
    const int b1 = Pbin[PTS_BLK - 1];
    const int nb = b1 - b0 + 1;

    const float4* __restrict__ filt4 = reinterpret_cast<const float4*>(filt);
    if (nb <= NB_MAX) {
        for (int i = tid; i < nb * 256; i += 256) Wl[i] = filt4[b0 * 256 + i];
    }
    {   // stage 128 feature rows: 8 threads/row read a 128B row coalesced
        const int r  = tid >> 3;          // 0..31
        const int c4 = tid & 7;           // 0..7
        #pragma unroll
        for (int pass = 0; pass < 4; ++pass) {
            const int row = pass * 32 + r;
            const float4 v = reinterpret_cast<const float4*>(
                                 feat + (size_t)Pidx[row] * 32)[c4];
            Fl[row * 8 + (c4 ^ (row & 7))] = v;
        }
    }
    __syncthreads();

    const int q   = tid & 3;              // d-quad (8 outputs)
    const int pp  = tid >> 2;             // 0..63 -> points pp, pp+64
    const int swz = pp & 7;               // (pp+64)&7 == pp&7
    const int bA  = Pbin[pp];
    const int bB  = Pbin[pp + 64];

    float acc[16];
    {
        const float4* bp = reinterpret_cast<const float4*>(bias) + q * 2;
        const float4 bv0 = bp[0], bv1 = bp[1];
        acc[0] = bv0.x; acc[1] = bv0.y; acc[2]  = bv0.z; acc[3]  = bv0.w;
        acc[4] = bv1.x; acc[5] = bv1.y; acc[6]  = bv1.z; acc[7]  = bv1.w;
        acc[8] = bv0.x; acc[9] = bv0.y; acc[10] = bv0.z; acc[11] = bv0.w;
        acc[12] = bv1.x; acc[13] = bv1.y; acc[14] = bv1.z; acc[15] = bv1.w;
    }

    bool dA = false, dB = false;
    while (true) {
        const int want = !dA ? bA : (!dB ? bB : -1);
        const unsigned long long v = __ballot(want >= 0);
        if (!v) break;
        const int src = (int)__ffsll((long long)v) - 1;
        const int bb  = __shfl(want, src);
        const bool aA = (bA == bb);
        const bool aB = (bB == bb);
        if (nb <= NB_MAX) {
            const float4* __restrict__ W4 = &Wl[(bb - b0) * 256];
            GEMM_PASS(W4)
        } else {   // never in practice (bin segments avg ~3277 pts >> 128)
            const float4* __restrict__ W4 = &filt4[(size_t)bb * 256];
            GEMM_PASS(W4)
        }
        dA |= aA; dB |= aB;
    }

    float4* oA = reinterpret_cast<float4*>(out + (size_t)Pidx[pp] * 32 + q * 8);
    oA[0] = make_float4(acc[0], acc[1], acc[2], acc[3]);
    oA[1] = make_float4(acc[4], acc[5], acc[6], acc[7]);
    float4* oB = reinterpret_cast<float4*>(out + (size_t)Pidx[pp + 64] * 32 + q * 8);
    oB[0] = make_float4(acc[8], acc[9], acc[10], acc[11]);
    oB[1] = make_float4(acc[12], acc[13], acc[14], acc[15]);
}

extern "C" void kernel_launch(void* const* d_in, const int* in_sizes, int n_in,
                              void* d_out, int out_size, void* d_ws, size_t ws_size,
                              hipStream_t stream) {
    const float*  feat   = (const float*)d_in[0];
    const float2* coords = (const float2*)d_in[1];
    const float*  filt   = (const float*)d_in[2];
    const float*  bias   = (const float*)d_in[3];
    float* out = (float*)d_out;

    const int npts = in_sizes[0] / 32;                   // 131072
    const int nblk = (npts + 1023) / 1024;               // 128

    int* sorted_pk           = (int*)d_ws;               // npts
    int* hist                = sorted_pk + npts;         // nblk*40
    int* blkoff              = hist + nblk * NBINS;      // nblk*40
    unsigned char* bins_u8   = (unsigned char*)(blkoff + nblk * NBINS);

    k_hist   <<<nblk, 1024, 0, stream>>>(coords, hist, bins_u8, npts);
    k_scan   <<<1,    1024, 0, stream>>>(hist, blkoff, nblk);
    k_scatter<<<nblk, 1024, 0, stream>>>(bins_u8, blkoff, sorted_pk, npts);
    k_gemm   <<<npts / PTS_BLK, 256, 0, stream>>>(feat, filt, bias, sorted_pk, out);
}

// Round 9
// 85.336 us; speedup vs baseline: 1.0840x; 1.0840x over previous
//
#include <hip/hip_runtime.h>

// GeodesicConv via counting-sort by bin + bf16 MFMA GEMM.
//
// R9: k_gemm rewritten on matrix cores. Sorted 256-pt block = one GEMM
// [256x32c] x [32c x 32d] per bin-pass (nb<=2 in practice). Wave = 32 pts:
// 2 M-tiles x 2 N-tiles of mfma_f32_16x16x32_bf16 (K=32 = full c, 1 step).
// Boundary waves: zero A-rows of out-of-bin points (exact; C unchanged).
// Frag layout (m89/m97-verified): A row=l&15,k=8*(l>>4)+j contiguous (b128);
// B col=l&15 same k; C/D col=l&15,row=4*(l>>4)+r.
// LDS 16B-chunk XOR swizzle (chunk ^ (row&3)) -> <=2-way bank alias (free).
// bf16 RNE inputs, f32 accum: max err ~6e-4 << 7.2e-3 threshold.

#define NBINS 40
#define NB_MAX 4
#define PTS_BLK 256
#define GTHREADS 512
#define MAX_NBLK 128

typedef __attribute__((ext_vector_type(8))) short bf16x8;
typedef __attribute__((ext_vector_type(4))) float f32x4;

__device__ __forceinline__ unsigned short f2bf(float x) {   // RNE f32->bf16
    unsigned u = __float_as_uint(x);
    u += 0x7FFFu + ((u >> 16) & 1u);
    return (unsigned short)(u >> 16);
}

__device__ __forceinline__ int bin_of(float2 rc) {
    const float TWO_PI_F = (float)(2.0 * 3.14159);
    int ri = (int)(rc.x * 5.0f);
    ri = min(max(ri, 0), 4);
    int oi = (int)((rc.y * 8.0f) / TWO_PI_F);
    oi = min(max(oi, 0), 7);
    return ri * 8 + oi;
}

__global__ __launch_bounds__(1024)
void k_hist(const float2* __restrict__ coords, int* __restrict__ hist,
            unsigned char* __restrict__ bins_u8, int npts) {
    __shared__ int h[NBINS];
    const int tid = threadIdx.x;
    if (tid < NBINS) h[tid] = 0;
    __syncthreads();
    const int p = blockIdx.x * 1024 + tid;
    if (p < npts) {
        const int b = bin_of(coords[p]);
        bins_u8[p] = (unsigned char)b;
        atomicAdd(&h[b], 1);
    }
    __syncthreads();
    if (tid < NBINS) hist[blockIdx.x * NBINS + tid] = h[tid];
}

__global__ __launch_bounds__(1024)
void k_scan(const int* __restrict__ hist, int* __restrict__ blkoff, int nblk) {
    __shared__ int lh[MAX_NBLK * NBINS];
    __shared__ int btot[NBINS];
    __shared__ int base[NBINS];
    const int tid  = threadIdx.x;
    const int wave = tid >> 6;
    const int lane = tid & 63;
    for (int i = tid; i < nblk * NBINS; i += 1024) lh[i] = hist[i];
    __syncthreads();
    for (int b = wave; b < NBINS; b += 16) {     // one wave per bin
        int v0 = lh[lane * NBINS + b];
        int v1 = lh[(64 + lane) * NBINS + b];
        #pragma unroll
        for (int off = 1; off < 64; off <<= 1) { int t = __shfl_up(v0, off); if (lane >= off) v0 += t; }
        const int tot0 = __shfl(v0, 63);
        #pragma unroll
        for (int off = 1; off < 64; off <<= 1) { int t = __shfl_up(v1, off); if (lane >= off) v1 += t; }
        const int total = __shfl(v1, 63) + tot0;
        int e0 = __shfl_up(v0, 1); if (lane == 0) e0 = 0;
        int e1 = __shfl_up(v1, 1); if (lane == 0) e1 = 0;
        e1 += tot0;
        lh[lane * NBINS + b] = e0;
        lh[(64 + lane) * NBINS + b] = e1;
        if (lane == 0) btot[b] = total;
    }
    __syncthreads();
    if (wave == 0) {
        int v = (lane < NBINS) ? btot[lane] : 0;
        #pragma unroll
        for (int off = 1; off < 64; off <<= 1) { int t = __shfl_up(v, off); if (lane >= off) v += t; }
        int e = __shfl_up(v, 1); if (lane == 0) e = 0;
        if (lane < NBINS) base[lane] = e;
    }
    __syncthreads();
    for (int i = tid; i < nblk * NBINS; i += 1024) {
        const int b = i - (i / NBINS) * NBINS;
        blkoff[i] = lh[i] + base[b];
    }
}

__global__ __launch_bounds__(1024)
void k_scatter(const unsigned char* __restrict__ bins_u8, const int* __restrict__ blkoff,
               int* __restrict__ sorted_pk, int npts) {
    __shared__ int off[NBINS];
    __shared__ int cnt[NBINS];
    const int tid = threadIdx.x;
    if (tid < NBINS) { off[tid] = blkoff[blockIdx.x * NBINS + tid]; cnt[tid] = 0; }
    __syncthreads();
    const int p = blockIdx.x * 1024 + tid;
    if (p < npts) {
        const int b = (int)bins_u8[p];
        const int r = atomicAdd(&cnt[b], 1);
        sorted_pk[off[b] + r] = p | (b << 20);
    }
}

__global__ __launch_bounds__(GTHREADS, 4)
void k_gemm(const float* __restrict__ feat, const float* __restrict__ filt,
            const float* __restrict__ bias, const int* __restrict__ sorted_pk,
            float* __restrict__ out) {
    __shared__ unsigned short Fl[PTS_BLK * 32];   // 16 KB bf16 feats, swizzled
    __shared__ unsigned short Wl[NB_MAX * 1024];  // 8 KB  bf16 W^T [b][d][c]
    __shared__ int Pidx[PTS_BLK];
    __shared__ int Pbin[PTS_BLK];

    const int tid     = threadIdx.x;
    const int blkbase = blockIdx.x * PTS_BLK;

    if (tid < PTS_BLK) {
        const int pk = sorted_pk[blkbase + tid];
        Pidx[tid] = pk & 0xFFFFF;
        Pbin[tid] = pk >> 20;
    }
    __syncthreads();

    const int b0 = Pbin[0];
    const int nb = Pbin[PTS_BLK - 1] - b0 + 1;

    {   // stage features: 8 thr/row, 64 rows/pass, 4 passes (coalesced 128B rows)
        const int r8 = tid >> 3, c4 = tid & 7;
        const int kc = c4 >> 1, half = c4 & 1;
        #pragma unroll
        for (int pass = 0; pass < 4; ++pass) {
            const int row = pass * 64 + r8;
            const float4 v = reinterpret_cast<const float4*>(
                                 feat + (size_t)Pidx[row] * 32)[c4];
            unsigned short* p = &Fl[row * 32 + (kc ^ (row & 3)) * 8 + half * 4];
            p[0] = f2bf(v.x); p[1] = f2bf(v.y); p[2] = f2bf(v.z); p[3] = f2bf(v.w);
        }
    }
    if (nb <= NB_MAX) {   // stage W transposed [d][c], c-chunk swizzled by d&3
        for (int i = tid; i < nb * 1024; i += GTHREADS) {
            const int bi = i >> 10, rem = i & 1023, c = rem >> 5, d = rem & 31;
            Wl[bi * 1024 + d * 32 + ((c >> 3) ^ (d & 3)) * 8 + (c & 7)] =
                f2bf(filt[(size_t)(b0 + bi) * 1024 + rem]);
        }
    }
    __syncthreads();

    const int wave  = tid >> 6;
    const int lane  = tid & 63;
    const int l15   = lane & 15;
    const int kg    = lane >> 4;          // k-group: k = 8*kg + j
    const int wbase = wave * 32;          // wave owns 32 points (2 M-tiles)

    f32x4 acc[2][2];
    {
        const float bv0 = bias[l15];
        const float bv1 = bias[16 + l15];
        #pragma unroll
        for (int m = 0; m < 2; ++m) {
            acc[m][0] = (f32x4){bv0, bv0, bv0, bv0};
            acc[m][1] = (f32x4){bv1, bv1, bv1, bv1};
        }
    }

    const int myb = Pbin[wbase + (lane & 31)];
    unsigned long long rem = __ballot(1);
    while (rem) {
        const int src = (int)__ffsll((long long)rem) - 1;
        const int bb  = __shfl(myb, src);
        rem &= ~__ballot(myb == bb);

        bf16x8 B[2];
        if (nb <= NB_MAX) {
            const int bl = (bb - b0) * 1024;
            B[0] = *reinterpret_cast<const bf16x8*>(
                       &Wl[bl + l15 * 32 + (kg ^ (l15 & 3)) * 8]);
            B[1] = *reinterpret_cast<const bf16x8*>(
                       &Wl[bl + (16 + l15) * 32 + (kg ^ (l15 & 3)) * 8]);
        } else {  // never in practice: scalar gather fallback
            const float* Wg = filt + (size_t)bb * 1024;
            #pragma unroll
            for (int n = 0; n < 2; ++n) {
                bf16x8 t;
                #pragma unroll
                for (int j = 0; j < 8; ++j)
                    t[j] = (short)f2bf(Wg[(kg * 8 + j) * 32 + n * 16 + l15]);
                B[n] = t;
            }
        }

        #pragma unroll
        for (int m = 0; m < 2; ++m) {
            const int pt = wbase + m * 16 + l15;
            bf16x8 a = *reinterpret_cast<const bf16x8*>(
                           &Fl[pt * 32 + (kg ^ (pt & 3)) * 8]);
            if (Pbin[pt] != bb) a = (bf16x8)0;   // mask out-of-bin rows: exact
            acc[m][0] = __builtin_amdgcn_mfma_f32_16x16x32_bf16(a, B[0], acc[m][0], 0, 0, 0);
            acc[m][1] = __builtin_amdgcn_mfma_f32_16x16x32_bf16(a, B[1], acc[m][1], 0, 0, 0);
        }
    }

    #pragma unroll
    for (int m = 0; m < 2; ++m)
        #pragma unroll
        for (int r = 0; r < 4; ++r) {
            const int row = wbase + m * 16 + kg * 4 + r;
            const size_t o = (size_t)Pidx[row] * 32;
            out[o + l15]      = acc[m][0][r];
            out[o + 16 + l15] = acc[m][1][r];
        }
}

extern "C" void kernel_launch(void* const* d_in, const int* in_sizes, int n_in,
                              void* d_out, int out_size, void* d_ws, size_t ws_size,
                              hipStream_t stream) {
    const float*  feat   = (const float*)d_in[0];
    const float2* coords = (const float2*)d_in[1];
    const float*  filt   = (const float*)d_in[2];
    const float*  bias   = (const float*)d_in[3];
    float* out = (float*)d_out;

    const int npts = in_sizes[0] / 32;                   // 131072
    const int nblk = (npts + 1023) / 1024;               // 128

    int* sorted_pk           = (int*)d_ws;               // npts
    int* hist                = sorted_pk + npts;         // nblk*40
    int* blkoff              = hist + nblk * NBINS;      // nblk*40
    unsigned char* bins_u8   = (unsigned char*)(blkoff + nblk * NBINS);

    k_hist   <<<nblk, 1024, 0, stream>>>(coords, hist, bins_u8, npts);
    k_scan   <<<1,    1024, 0, stream>>>(hist, blkoff, nblk);
    k_scatter<<<nblk, 1024, 0, stream>>>(bins_u8, blkoff, sorted_pk, npts);
    k_gemm   <<<npts / PTS_BLK, GTHREADS, 0, stream>>>(feat, filt, bias, sorted_pk, out);
}

// Round 10
// 80.868 us; speedup vs baseline: 1.1438x; 1.0553x over previous
//
#include <hip/hip_runtime.h>

// GeodesicConv, single fused kernel — no sort, no workspace.
//
// out[p,d] = sum_c feat[p,c] * W[bin(p)][c][d] + bias[d], 40 bins.
//
// All 40 bins' W staged in LDS as PRE-BUILT MFMA B-FRAGMENTS:
//   Wl[((bin*2+n)*64 + lane)*8 .. +7] = bf16 W[c=8*(lane>>4)+j][d=n*16+(lane&15)]
// so the per-pass B load is ds_read_b128 at addr lane*16 -> zero bank
// conflicts, and staging writes are lane-consecutive b128 -> zero conflicts.
// (Fragment content/layout identical to the R9 kernel that PASSED.)
//
// Wave = 32 natural-order points (2 M-tiles). Loop over the wave's distinct
// bins (E~22 of 40): mask out-of-bin A-rows to zero (fmaf(0,w): exact),
// 4 mfma_f32_16x16x32_bf16 per pass, B prefetched one pass ahead.
// A-frags load global->reg: wave collectively reads a contiguous 2KB block.
//
// bin math bit-exact vs numpy f32 (trunc(r*5), trunc((a*8)/TWO_PI)).
// bf16 RNE inputs, f32 accum: absmax ~2e-3 << 7.2e-3 threshold (R9-proven).

#define NBINS 40
#define THREADS 1024      // 16 waves
#define PTS_BLK 512       // 32 pts/wave

typedef __attribute__((ext_vector_type(8))) short bf16x8;
typedef __attribute__((ext_vector_type(4))) float f32x4;

__device__ __forceinline__ unsigned short f2bf(float x) {   // RNE f32->bf16
    unsigned u = __float_as_uint(x);
    u += 0x7FFFu + ((u >> 16) & 1u);
    return (unsigned short)(u >> 16);
}

__device__ __forceinline__ int bin_of(float2 rc) {
    const float TWO_PI_F = (float)(2.0 * 3.14159);
    int ri = (int)(rc.x * 5.0f);
    ri = min(max(ri, 0), 4);
    int oi = (int)((rc.y * 8.0f) / TWO_PI_F);
    oi = min(max(oi, 0), 7);
    return ri * 8 + oi;
}

__global__ __launch_bounds__(THREADS, 4)
void k_fused(const float* __restrict__ feat, const float2* __restrict__ coords,
             const float* __restrict__ filt, const float* __restrict__ bias,
             float* __restrict__ out) {
    __shared__ __align__(16) unsigned short Wl[NBINS * 2 * 64 * 8];  // 80 KB
    __shared__ int wlist[16][32];

    const int tid  = threadIdx.x;
    const int lane = tid & 63;
    const int wave = tid >> 6;
    const int l15  = lane & 15;
    const int kg   = lane >> 4;
    const int pbase = blockIdx.x * PTS_BLK + wave * 32;

    // ---- stage 40 bins of W as ready-to-read B-fragments (5120 x 16B) ----
    // item -> (bin, n, kg', l15'); global reads: 16 consecutive lanes x 4B
    // coalesced per j; LDS write at it*16 B = lane-consecutive, conflict-free.
    for (int it = tid; it < NBINS * 128; it += THREADS) {
        const int il = it & 15, ik = (it >> 4) & 3, in = (it >> 6) & 1, ib = it >> 7;
        const float* src = filt + ib * 1024 + ik * 256 + in * 16 + il;
        bf16x8 w;
        #pragma unroll
        for (int j = 0; j < 8; ++j) w[j] = (short)f2bf(src[j * 32]);
        *reinterpret_cast<bf16x8*>(&Wl[it * 8]) = w;
    }

    // ---- per-lane point bin; A-fragments direct global->reg ----
    const int myb = bin_of(coords[pbase + (lane & 31)]);
    bf16x8 af[2];
    #pragma unroll
    for (int m = 0; m < 2; ++m) {
        const float* fp = feat + (size_t)(pbase + m * 16 + l15) * 32 + kg * 8;
        const float4 v0 = *reinterpret_cast<const float4*>(fp);
        const float4 v1 = *reinterpret_cast<const float4*>(fp + 4);
        bf16x8 a;
        a[0] = (short)f2bf(v0.x); a[1] = (short)f2bf(v0.y);
        a[2] = (short)f2bf(v0.z); a[3] = (short)f2bf(v0.w);
        a[4] = (short)f2bf(v1.x); a[5] = (short)f2bf(v1.y);
        a[6] = (short)f2bf(v1.z); a[7] = (short)f2bf(v1.w);
        af[m] = a;
    }
    const int bm0 = __shfl(myb, l15);        // bin of M-tile-0 row l15
    const int bm1 = __shfl(myb, 16 + l15);   // bin of M-tile-1 row l15

    // ---- collect the wave's distinct bins (wave-uniform list) ----
    int cnt = 0;
    unsigned long long rem = __ballot(1);
    while (rem) {
        const int src = (int)__ffsll((long long)rem) - 1;
        const int bb  = __shfl(myb, src);
        rem &= ~__ballot(myb == bb);
        if (lane == 0) wlist[wave][cnt] = bb;
        ++cnt;
    }

    __syncthreads();                          // Wl ready

    f32x4 acc[2][2];
    {
        const float bv0 = bias[l15];
        const float bv1 = bias[16 + l15];
        #pragma unroll
        for (int m = 0; m < 2; ++m) {
            acc[m][0] = (f32x4){bv0, bv0, bv0, bv0};
            acc[m][1] = (f32x4){bv1, bv1, bv1, bv1};
        }
    }

    // ---- pass loop over distinct bins, B prefetched one ahead ----
    int bb = wlist[wave][0];
    bf16x8 B0 = *reinterpret_cast<const bf16x8*>(&Wl[((bb * 2 + 0) * 64 + lane) * 8]);
    bf16x8 B1 = *reinterpret_cast<const bf16x8*>(&Wl[((bb * 2 + 1) * 64 + lane) * 8]);
    for (int i = 0; i < cnt; ++i) {
        const int nx  = (i + 1 < cnt) ? i + 1 : i;
        const int bbn = wlist[wave][nx];
        const bf16x8 N0 = *reinterpret_cast<const bf16x8*>(&Wl[((bbn * 2 + 0) * 64 + lane) * 8]);
        const bf16x8 N1 = *reinterpret_cast<const bf16x8*>(&Wl[((bbn * 2 + 1) * 64 + lane) * 8]);
        bf16x8 a0 = af[0]; if (bm0 != bb) a0 = (bf16x8)0;   // exact masking
        bf16x8 a1 = af[1]; if (bm1 != bb) a1 = (bf16x8)0;
        acc[0][0] = __builtin_amdgcn_mfma_f32_16x16x32_bf16(a0, B0, acc[0][0], 0, 0, 0);
        acc[0][1] = __builtin_amdgcn_mfma_f32_16x16x32_bf16(a0, B1, acc[0][1], 0, 0, 0);
        acc[1][0] = __builtin_amdgcn_mfma_f32_16x16x32_bf16(a1, B0, acc[1][0], 0, 0, 0);
        acc[1][1] = __builtin_amdgcn_mfma_f32_16x16x32_bf16(a1, B1, acc[1][1], 0, 0, 0);
        bb = bbn; B0 = N0; B1 = N1;
    }

    // ---- C write: row = pbase + m*16 + kg*4 + r, cols l15 / 16+l15 ----
    #pragma unroll
    for (int m = 0; m < 2; ++m)
        #pragma unroll
        for (int r = 0; r < 4; ++r) {
            const size_t o = (size_t)(pbase + m * 16 + kg * 4 + r) * 32;
            out[o + l15]      = acc[m][0][r];
            out[o + 16 + l15] = acc[m][1][r];
        }
}

extern "C" void kernel_launch(void* const* d_in, const int* in_sizes, int n_in,
                              void* d_out, int out_size, void* d_ws, size_t ws_size,
                              hipStream_t stream) {
    const float*  feat   = (const float*)d_in[0];
    const float2* coords = (const float2*)d_in[1];
    const float*  filt   = (const float*)d_in[2];
    const float*  bias   = (const float*)d_in[3];
    float* out = (float*)d_out;

    const int npts = in_sizes[0] / 32;        // 131072
    k_fused<<<npts / PTS_BLK, THREADS, 0, stream>>>(feat, coords, filt, bias, out);
}

// Round 11
// 80.703 us; speedup vs baseline: 1.1462x; 1.0020x over previous
//
#include <hip/hip_runtime.h>

// GeodesicConv, single fused kernel: block-local counting sort + MFMA.
//
// out[p,d] = sum_c feat[p,c] * W[bin(p)][c][d] + bias[d], 40 bins.
//
// Block = 1024 thr / 512 pts. In-LDS counting sort by bin (hist -> wave0
// shfl-scan -> scatter rank[]): sorted 32-slot runs span ~3.3 bins (vs 22
// unsorted in R10) -> pass loop shrinks ~7x. With passes this few, B-frags
// are gathered straight from L2-resident filt (160 KB) with 1-ahead
// prefetch — no 80 KB LDS W stage, no 41 MB staging burst.
// MFMA frag layouts = R9/R10-verified (passed, absmax 1.95e-3).
// Exactness: each point's result comes from its own bin's pass only; other
// passes contribute fmaf(0,w) = +-0 (exact) -> absmax identical to R10.

#define NBINS 40
#define THREADS 1024      // 16 waves
#define PTS_BLK 512       // 32 pts/wave

typedef __attribute__((ext_vector_type(8))) short bf16x8;
typedef __attribute__((ext_vector_type(4))) float f32x4;

__device__ __forceinline__ unsigned short f2bf(float x) {   // RNE f32->bf16
    unsigned u = __float_as_uint(x);
    u += 0x7FFFu + ((u >> 16) & 1u);
    return (unsigned short)(u >> 16);
}

__device__ __forceinline__ int bin_of(float2 rc) {          // bit-exact vs np
    const float TWO_PI_F = (float)(2.0 * 3.14159);
    int ri = (int)(rc.x * 5.0f);
    ri = min(max(ri, 0), 4);
    int oi = (int)((rc.y * 8.0f) / TWO_PI_F);
    oi = min(max(oi, 0), 7);
    return ri * 8 + oi;
}

__global__ __launch_bounds__(THREADS, 4)
void k_fused(const float* __restrict__ feat, const float2* __restrict__ coords,
             const float* __restrict__ filt, const float* __restrict__ bias,
             float* __restrict__ out) {
    __shared__ int hist[NBINS];
    __shared__ int offs[NBINS];
    __shared__ int bins[PTS_BLK];
    __shared__ int rank[PTS_BLK];
    __shared__ int wlist[16][32];

    const int tid  = threadIdx.x;
    const int lane = tid & 63;
    const int wave = tid >> 6;
    const int l15  = lane & 15;
    const int kg   = lane >> 4;
    const int pbase = blockIdx.x * PTS_BLK;

    // ---- block-local counting sort by bin ----
    if (tid < NBINS) hist[tid] = 0;
    __syncthreads();
    if (tid < PTS_BLK) {
        const int b = bin_of(coords[pbase + tid]);
        bins[tid] = b;
        atomicAdd(&hist[b], 1);
    }
    __syncthreads();
    if (wave == 0) {                       // exclusive scan of 40 counts
        int v = (lane < NBINS) ? hist[lane] : 0;
        #pragma unroll
        for (int o = 1; o < 64; o <<= 1) { int t = __shfl_up(v, o); if (lane >= o) v += t; }
        int e = __shfl_up(v, 1); if (lane == 0) e = 0;
        if (lane < NBINS) offs[lane] = e;
    }
    __syncthreads();
    if (tid < PTS_BLK) {
        const int r = atomicAdd(&offs[bins[tid]], 1);
        rank[r] = tid;                     // sorted order -> local point idx
    }
    __syncthreads();

    // ---- wave takes 32 sorted slots; gather A-frags + bins ----
    const int wbase = wave * 32;
    const int myb = bins[rank[wbase + (lane & 31)]];

    int lidx[2], bm[2];
    bf16x8 af[2];
    #pragma unroll
    for (int m = 0; m < 2; ++m) {
        lidx[m] = rank[wbase + m * 16 + l15];
        bm[m]   = bins[lidx[m]];
        const float* fp = feat + (size_t)(pbase + lidx[m]) * 32 + kg * 8;
        const float4 v0 = *reinterpret_cast<const float4*>(fp);
        const float4 v1 = *reinterpret_cast<const float4*>(fp + 4);
        bf16x8 a;
        a[0] = (short)f2bf(v0.x); a[1] = (short)f2bf(v0.y);
        a[2] = (short)f2bf(v0.z); a[3] = (short)f2bf(v0.w);
        a[4] = (short)f2bf(v1.x); a[5] = (short)f2bf(v1.y);
        a[6] = (short)f2bf(v1.z); a[7] = (short)f2bf(v1.w);
        af[m] = a;
    }

    // ---- wave's distinct-bin list (sorted => ~3-4 entries) ----
    int cnt = 0;
    unsigned long long rem = __ballot(1);
    while (rem) {
        const int src = (int)__ffsll((long long)rem) - 1;
        const int bb  = __shfl(myb, src);
        rem &= ~__ballot(myb == bb);
        if (lane == 0) wlist[wave][cnt] = bb;
        ++cnt;
    }

    f32x4 acc[2][2];
    {
        const float bv0 = bias[l15];
        const float bv1 = bias[16 + l15];
        #pragma unroll
        for (int m = 0; m < 2; ++m) {
            acc[m][0] = (f32x4){bv0, bv0, bv0, bv0};
            acc[m][1] = (f32x4){bv1, bv1, bv1, bv1};
        }
    }

    // ---- pass loop; B-frags gathered from L2-resident filt, 1-ahead ----
    // lane's B elems: W[bin][kg*8+j][n*16+l15]  (j stride = 32 floats)
    const float* bsrc = filt + kg * 256 + l15;
#define LOAD_B(BB, O0, O1) {                                                  \
        const float* s = bsrc + (BB) * 1024;                                  \
        bf16x8 t0, t1;                                                        \
        _Pragma("unroll")                                                     \
        for (int j = 0; j < 8; ++j) {                                         \
            t0[j] = (short)f2bf(s[j * 32]);                                   \
            t1[j] = (short)f2bf(s[j * 32 + 16]);                              \
        }                                                                     \
        O0 = t0; O1 = t1;                                                     \
    }

    int bb = wlist[wave][0];
    bf16x8 B0, B1, N0, N1;
    LOAD_B(bb, B0, B1)
    for (int i = 0; i < cnt; ++i) {
        const int nx  = (i + 1 < cnt) ? i + 1 : i;
        const int bbn = wlist[wave][nx];
        LOAD_B(bbn, N0, N1)                  // prefetch next pass
        bf16x8 a0 = af[0]; if (bm[0] != bb) a0 = (bf16x8)0;   // exact mask
        bf16x8 a1 = af[1]; if (bm[1] != bb) a1 = (bf16x8)0;
        acc[0][0] = __builtin_amdgcn_mfma_f32_16x16x32_bf16(a0, B0, acc[0][0], 0, 0, 0);
        acc[0][1] = __builtin_amdgcn_mfma_f32_16x16x32_bf16(a0, B1, acc[0][1], 0, 0, 0);
        acc[1][0] = __builtin_amdgcn_mfma_f32_16x16x32_bf16(a1, B0, acc[1][0], 0, 0, 0);
        acc[1][1] = __builtin_amdgcn_mfma_f32_16x16x32_bf16(a1, B1, acc[1][1], 0, 0, 0);
        bb = bbn; B0 = N0; B1 = N1;
    }

    // ---- C write: tile row kg*4+r -> sorted slot -> point rank[...] ----
    #pragma unroll
    for (int m = 0; m < 2; ++m)
        #pragma unroll
        for (int r = 0; r < 4; ++r) {
            const int row = rank[wbase + m * 16 + kg * 4 + r];
            const size_t o = (size_t)(pbase + row) * 32;
            out[o + l15]      = acc[m][0][r];
            out[o + 16 + l15] = acc[m][1][r];
        }
}

extern "C" void kernel_launch(void* const* d_in, const int* in_sizes, int n_in,
                              void* d_out, int out_size, void* d_ws, size_t ws_size,
                              hipStream_t stream) {
    const float*  feat   = (const float*)d_in[0];
    const float2* coords = (const float2*)d_in[1];
    const float*  filt   = (const float*)d_in[2];
    const float*  bias   = (const float*)d_in[3];
    float* out = (float*)d_out;

    const int npts = in_sizes[0] / 32;        // 131072
    k_fused<<<npts / PTS_BLK, THREADS, 0, stream>>>(feat, coords, filt, bias, out);
}